// Round 8
// baseline (1614.970 us; speedup 1.0000x reference)
//
#include <hip/hip_runtime.h>
#include <hip/hip_bf16.h>

#define BB 256      // batch
#define TT 2048     // timesteps
#define DD 32       // obs dim
#define HH 64       // hidden
#define GG 256      // 4*H gates

__device__ __forceinline__ float fast_sig(float x) {
    return __builtin_amdgcn_rcpf(1.0f + __expf(-x));
}
__device__ __forceinline__ float rdlane(float v, int k) {
    return __uint_as_float(__builtin_amdgcn_readlane(__float_as_uint(v), k));
}
// LDS-only barrier: drain lgkmcnt, leave global loads/stores in flight.
__device__ __forceinline__ void lds_barrier() {
    asm volatile("s_waitcnt lgkmcnt(0)" ::: "memory");
    __builtin_amdgcn_s_barrier();
    asm volatile("" ::: "memory");
}

// 8 waves per batch element: wave = (gate w in 0..3) x (K-half in 0..1).
// Each wave computes a 64-wide PRE-ACTIVATION partial sum (x-half + h-half),
// exchanges partials through gbuf[8][64] (conflict-free b32s), then EVERY
// wave redundantly reconstructs all 4 gates, applies the 4 activations in
// parallel (single trans-chain depth), and updates its in-register replica
// of (c[l], h[l]). h feeds the next GEMV via readlane from own registers --
// h/c never touch LDS. One lgkm-barrier per step; double-buffered gbuf.
__global__ __launch_bounds__(512, 1) void lstm_splitk_kernel(
    const float* __restrict__ y,    // [B, T, D]
    const float* __restrict__ Wx,   // [D, 4H]
    const float* __restrict__ Wh,   // [H, 4H]
    const float* __restrict__ b,    // [4H]
    float* __restrict__ out)        // [B, T, H]
{
    const int tid = threadIdx.x;
    const int wv  = tid >> 6;        // wave 0..7
    const int w   = wv >> 1;         // gate type 0..3 (i,f,g,o)
    const int hf  = wv & 1;          // K-half 0..1
    const int l   = tid & 63;        // lane = hidden unit
    const int batch = blockIdx.x;
    const int j   = w * HH + l;      // gate column in [0,256)

    __shared__ float gbuf[2][8][HH];   // [buf][wave][unit] partial sums, 4 KB

    // ---- per-lane weight slices (coalesced: fixed row, consecutive j)
    float wh[32];                      // Wh rows hf*32 .. hf*32+31, column j
#pragma unroll
    for (int kk = 0; kk < 32; ++kk) wh[kk] = Wh[(hf * 32 + kk) * GG + j];
    float wx[16];                      // Wx rows hf*16 .. hf*16+15, column j
#pragma unroll
    for (int d = 0; d < 16; ++d) wx[d] = Wx[(hf * 16 + d) * GG + j];
    const float bj = (hf == 0) ? b[j] : 0.0f;
    const int kbase = hf * 32;         // readlane base for the h-half

    float c = 0.0f, h = 0.0f;          // lane l's replica of c[l], h[l]

    const float* ybase = y + (size_t)batch * (TT * DD) + hf * 16;
    float* obase = out + (size_t)batch * (TT * HH);

    // x half-row (16 floats) double-buffered in registers
    float4 xa[4], xb[4];
    {
        const float4* r0 = (const float4*)ybase;
#pragma unroll
        for (int q = 0; q < 4; ++q) xa[q] = r0[q];
    }

    __syncthreads();   // once at init

#define STEP(XC, XN, BUFI, TI)                                                 \
    {                                                                          \
        /* prefetch next x half-row; stays in flight across the barrier */     \
        const int tn_ = ((TI) + 1 < TT) ? ((TI) + 1) : (TI);                   \
        const float4* nrow_ = (const float4*)(ybase + (size_t)tn_ * DD);       \
        _Pragma("unroll")                                                      \
        for (int q = 0; q < 4; ++q) XN[q] = nrow_[q];                          \
        /* partial pre-activation sum: x-half + h-half, 4-way ILP */           \
        float ac0 = bj, ac1 = 0.0f, ac2 = 0.0f, ac3 = 0.0f;                    \
        _Pragma("unroll")                                                      \
        for (int q = 0; q < 4; ++q) {                                          \
            ac0 = fmaf(XC[q].x, wx[4 * q + 0], ac0);                           \
            ac1 = fmaf(XC[q].y, wx[4 * q + 1], ac1);                           \
            ac2 = fmaf(XC[q].z, wx[4 * q + 2], ac2);                           \
            ac3 = fmaf(XC[q].w, wx[4 * q + 3], ac3);                           \
        }                                                                      \
        _Pragma("unroll")                                                      \
        for (int k4 = 0; k4 < 8; ++k4) {                                       \
            ac0 = fmaf(rdlane(h, kbase + 4 * k4 + 0), wh[4 * k4 + 0], ac0);    \
            ac1 = fmaf(rdlane(h, kbase + 4 * k4 + 1), wh[4 * k4 + 1], ac1);    \
            ac2 = fmaf(rdlane(h, kbase + 4 * k4 + 2), wh[4 * k4 + 2], ac2);    \
            ac3 = fmaf(rdlane(h, kbase + 4 * k4 + 3), wh[4 * k4 + 3], ac3);    \
        }                                                                      \
        gbuf[BUFI][wv][l] = (ac0 + ac1) + (ac2 + ac3);                         \
        lds_barrier();                                                         \
        /* reconstruct all 4 gates; 4 activation chains run ILP-parallel */    \
        float gi_ = gbuf[BUFI][0][l] + gbuf[BUFI][1][l];                       \
        float gf_ = gbuf[BUFI][2][l] + gbuf[BUFI][3][l];                       \
        float gg_ = gbuf[BUFI][4][l] + gbuf[BUFI][5][l];                       \
        float go_ = gbuf[BUFI][6][l] + gbuf[BUFI][7][l];                       \
        float ig_ = fast_sig(gi_);                                             \
        float fg_ = fast_sig(gf_);                                             \
        float gt_ = fmaf(2.0f, fast_sig(2.0f * gg_), -1.0f);   /* tanh */      \
        float og_ = fast_sig(go_);                                             \
        c = fmaf(fg_, c, ig_ * gt_);                                           \
        h = og_ * fmaf(2.0f, fast_sig(2.0f * c), -1.0f);       /* o*tanh(c) */ \
        if (wv == 0) obase[(size_t)(TI) * HH + l] = h;                         \
    }

    for (int t = 0; t < TT; t += 2) {
        STEP(xa, xb, 0, t);       // consume xa, prefetch xb
        STEP(xb, xa, 1, t + 1);   // consume xb, prefetch xa
    }
#undef STEP
}

extern "C" void kernel_launch(void* const* d_in, const int* in_sizes, int n_in,
                              void* d_out, int out_size, void* d_ws, size_t ws_size,
                              hipStream_t stream) {
    const float* y  = (const float*)d_in[0];
    const float* Wx = (const float*)d_in[1];
    const float* Wh = (const float*)d_in[2];
    const float* b  = (const float*)d_in[3];
    float* out = (float*)d_out;

    lstm_splitk_kernel<<<BB, 512, 0, stream>>>(y, Wx, Wh, b, out);
}